// Round 2
// baseline (662.222 us; speedup 1.0000x reference)
//
#include <hip/hip_runtime.h>

#define BB 16
#define CC 64
#define HH 256
#define WW 256
#define HWSZ 65536

// ws layout (floats):
// [0, 1024)             feat_ave[b*64+c]
// [1024, 17408)         kernP[(b*64+c)*16 + t]   (t<9 valid)
// [17408, 18432)        att[b*64+c]
// [18432, 22528)        cwT[c*64+o]  (= conv_w[o][c])

__global__ __launch_bounds__(256) void k_mean(const float* __restrict__ feat,
                                              float* __restrict__ fa) {
    int bc = blockIdx.x;  // 0..1023
    const float4* p = (const float4*)(feat + (size_t)bc * HWSZ);
    int t = threadIdx.x;
    float s = 0.f;
#pragma unroll
    for (int k = 0; k < 64; ++k) {
        float4 v = p[t + k * 256];
        s += v.x + v.y + v.z + v.w;
    }
#pragma unroll
    for (int off = 32; off; off >>= 1) s += __shfl_down(s, off);
    __shared__ float red[4];
    if ((t & 63) == 0) red[t >> 6] = s;
    __syncthreads();
    if (t == 0) {
        float tot = red[0] + red[1] + red[2] + red[3];
        fa[bc] = tot * (1.f / 65536.f);
    }
}

__global__ __launch_bounds__(64) void k_small(
    const float* __restrict__ fa, const float* __restrict__ deg,
    const float* __restrict__ wq, const float* __restrict__ bq,
    const float* __restrict__ wk, const float* __restrict__ bk,
    const float* __restrict__ wv, const float* __restrict__ bv,
    const float* __restrict__ gamma, const float* __restrict__ k_w1,
    const float* __restrict__ k_w2, const float* __restrict__ conv_w,
    const float* __restrict__ ca_w1, const float* __restrict__ ca_w2,
    float* __restrict__ kernP, float* __restrict__ att, float* __restrict__ cwT) {
    int b = blockIdx.x, j = threadIdx.x;
    __shared__ float s_fa[64], s_deg[64], s_k[64], s_v[64], s_emb[64], s_hid[64], s_ca[8];
    s_fa[j] = fa[b * 64 + j];
    s_deg[j] = deg[b * 64 + j];
    __syncthreads();
    float q = bq[j], kk = bk[j], vv = bv[j];
    for (int i = 0; i < 64; ++i) {
        q += s_fa[i] * wq[j * 64 + i];
        kk += s_deg[i] * wk[j * 64 + i];
        vv += s_deg[i] * wv[j * 64 + i];
    }
    s_k[j] = kk;
    s_v[j] = vv;
    __syncthreads();
    float m = -1e30f;
    for (int i = 0; i < 64; ++i) m = fmaxf(m, q * s_k[i]);
    float sum = 0.f, cma = 0.f;
    for (int i = 0; i < 64; ++i) {
        float e = expf(q * s_k[i] - m);
        sum += e;
        cma += s_v[i] * e;
    }
    cma /= sum;
    float emb = gamma[0] * cma + s_deg[j];
    s_emb[j] = emb;
    __syncthreads();
    float h = 0.f;
    for (int i = 0; i < 64; ++i) h += s_emb[i] * k_w1[j * 64 + i];
    h = h > 0.f ? h : 0.1f * h;
    s_hid[j] = h;
    if (j < 8) {
        float a = 0.f;
        for (int i = 0; i < 64; ++i) a += s_deg[i] * ca_w1[j * 64 + i];
        s_ca[j] = a > 0.f ? a : 0.1f * a;
    }
    __syncthreads();
#pragma unroll
    for (int t = 0; t < 9; ++t) {
        float kv = 0.f;
        for (int i = 0; i < 64; ++i) kv += s_hid[i] * k_w2[(j * 9 + t) * 64 + i];
        kernP[(b * 64 + j) * 16 + t] = kv;
    }
    float a2 = 0.f;
#pragma unroll
    for (int r = 0; r < 8; ++r) a2 += s_ca[r] * ca_w2[j * 8 + r];
    att[b * 64 + j] = 1.f / (1.f + expf(-a2));
    if (b == 0) {
        for (int o = 0; o < 64; ++o) cwT[j * 64 + o] = conv_w[o * 64 + j];
    }
}

__global__ __launch_bounds__(256, 4) void k_main(
    const float* __restrict__ feat, const float* __restrict__ conv_b,
    const float* __restrict__ kernP, const float* __restrict__ att,
    const float* __restrict__ cwT, float* __restrict__ out) {
    // XCD-bijective swizzle: 4096 blocks, 8 XCDs -> contiguous row ranges per XCD
    int bid = blockIdx.x;
    int per = (BB * HH) / 8;                 // 512
    int lin = (bid & 7) * per + (bid >> 3);
    int b = lin >> 8;
    int y = lin & 255;
    int x = threadIdx.x;

    const float* fb = feat + (size_t)b * CC * HWSZ;

    int y0 = y > 0 ? y - 1 : 0, y2 = y < 255 ? y + 1 : 255;
    int x0 = x > 0 ? x - 1 : 0, x2 = x < 255 ? x + 1 : 255;
    int ys[3] = {y0, y, y2};
    int xs[3] = {x0, x, x2};
    float ym[3] = {(y > 0) ? 1.f : 0.f, 1.f, (y < 255) ? 1.f : 0.f};
    float xm[3] = {(x > 0) ? 1.f : 0.f, 1.f, (x < 255) ? 1.f : 0.f};
    int off[9];
    float msk[9];
#pragma unroll
    for (int dy = 0; dy < 3; ++dy)
#pragma unroll
        for (int dx = 0; dx < 3; ++dx) {
            off[dy * 3 + dx] = ys[dy] * WW + xs[dx];
            msk[dy * 3 + dx] = ym[dy] * xm[dx];
        }

    const float* attb = att + b * 64;
    float acc[64];
#pragma unroll
    for (int o = 0; o < 64; ++o)
        acc[o] = conv_b[o] + attb[o] * fb[(size_t)o * HWSZ + y * WW + x];

    const float* kb = kernP + (size_t)b * 64 * 16;
    for (int c = 0; c < 64; ++c) {
        const float* fc = fb + (size_t)c * HWSZ;
        float g = 0.f;
#pragma unroll
        for (int t = 0; t < 9; ++t) g += kb[c * 16 + t] * (msk[t] * fc[off[t]]);
        g = g > 0.f ? g : 0.1f * g;
        const float* wc = cwT + c * 64;
#pragma unroll
        for (int o = 0; o < 64; ++o) acc[o] += wc[o] * g;
    }

    float* ob = out + (size_t)b * CC * HWSZ + y * WW + x;
#pragma unroll
    for (int o = 0; o < 64; ++o) ob[(size_t)o * HWSZ] = acc[o];
}

extern "C" void kernel_launch(void* const* d_in, const int* in_sizes, int n_in,
                              void* d_out, int out_size, void* d_ws, size_t ws_size,
                              hipStream_t stream) {
    const float* feat   = (const float*)d_in[0];
    const float* deg    = (const float*)d_in[1];
    const float* wq     = (const float*)d_in[2];
    const float* bq     = (const float*)d_in[3];
    const float* wk     = (const float*)d_in[4];
    const float* bk     = (const float*)d_in[5];
    const float* wv     = (const float*)d_in[6];
    const float* bv     = (const float*)d_in[7];
    const float* gamma  = (const float*)d_in[8];
    const float* k_w1   = (const float*)d_in[9];
    const float* k_w2   = (const float*)d_in[10];
    const float* conv_w = (const float*)d_in[11];
    const float* conv_b = (const float*)d_in[12];
    const float* ca_w1  = (const float*)d_in[13];
    const float* ca_w2  = (const float*)d_in[14];

    float* ws    = (float*)d_ws;
    float* fa    = ws;           // 1024
    float* kernP = ws + 1024;    // 16384
    float* attw  = ws + 17408;   // 1024
    float* cwT   = ws + 18432;   // 4096

    k_mean<<<1024, 256, 0, stream>>>(feat, fa);
    k_small<<<16, 64, 0, stream>>>(fa, deg, wq, bq, wk, bk, wv, bv, gamma,
                                   k_w1, k_w2, conv_w, ca_w1, ca_w2,
                                   kernP, attw, cwT);
    k_main<<<4096, 256, 0, stream>>>(feat, conv_b, kernP, attw, cwT, (float*)d_out);
}